// Round 16
// baseline (134.303 us; speedup 1.0000x reference)
//
#include <hip/hip_runtime.h>

// Multi-head VQ: inputs (16,2048,1024) f32, embeddings (4,64,256) f32.
// Out flat f32: quantized_st[33554432] | loss[1] | indices[131072 as float].
// R16 = R15 with TPB 32->16: LDS 50.7KB -> ~25.5KB raises the blocks/CU
// cap 3->6 (24 waves/CU = 75%); R15 was latency-bound at 2.4 waves/SIMD
// (VALUBusy 52%, both pipes half-idle). Numerics per token-head are
// byte-identical to R15. DPP all-reduce on VALU pipe (R15), 2-token
// unroll (R14), XSTR=324 skew (R14), dist_lds ascending-k scan (R12).
// quantized_st written as q directly (|x+(q-x)-q| ~1e-6 << 1.26 thr);
// loss = min distance (== ||q-x||^2 within ~1e-6 rel).

#define HH   4
#define KK   64
#define HD   256
#define DD   1024
#define NTOK 32768
#define NDQ  33554432ull
#define TPB  16            // tokens per block
#define NBX  (NTOK / TPB)  // 2048 blocks in x
#define NPART (NBX * HH)   // 8192 partials
#define XSTR 324           // floats per token row (16 slices * 20 + 4 skew)
#define DSTR 68            // padded float stride per-token dist row

template<int CTRL>
__device__ __forceinline__ float dpp_addstep(float v) {
    const int r = __builtin_amdgcn_update_dpp(
        0, __float_as_int(v), CTRL, 0xF, 0xF, true);
    return v + __int_as_float(r);
}
// Sum all-reduce within each 16-lane DPP row: xor1, xor2, ror4, ror8.
__device__ __forceinline__ float red16(float v) {
    v = dpp_addstep<0xB1>(v);    // quad_perm [1,0,3,2]  (xor 1)
    v = dpp_addstep<0x4E>(v);    // quad_perm [2,3,0,1]  (xor 2)
    v = dpp_addstep<0x124>(v);   // row_ror:4
    v = dpp_addstep<0x128>(v);   // row_ror:8
    return v;
}

__global__ void vq_cbq(const float* __restrict__ emb, float* __restrict__ cbq)
{
    const int t = threadIdx.x;               // one per (h,k)
    const float* e = emb + (size_t)t * HD;
    float s = 0.f;
    {
        #pragma clang fp contract(off)
        for (int d = 0; d < HD; ++d) {
            float p = e[d] * e[d];
            s = s + p;
        }
    }
    cbq[t] = s;
}

__global__ __launch_bounds__(256, 2) void vq_main(
    const float* __restrict__ x, const float* __restrict__ emb,
    const float* __restrict__ cbq, float* __restrict__ out,
    double* __restrict__ partial)
{
    __shared__ __align__(16) float x_lds[TPB * XSTR];      // 20736 B
    __shared__ __align__(16) float dist_lds[TPB * DSTR];   //  4352 B
    __shared__ float isq_lds[TPB];
    __shared__ int   bi_lds[TPB];

    const int h    = blockIdx.y;
    const int wv   = threadIdx.x >> 6;
    const int lane = threadIdx.x & 63;
    const int tok0 = blockIdx.x * TPB;

    const float* __restrict__ eh = emb + (size_t)h * (KK * HD);

    // ---- Phase A: lane holds 4 codes x 16 dims of e (16 float4) ----
    const int kq = lane >> 4;          // 0..3 code quad within wave slab
    const int ds = lane & 15;          // 0..15 dim slice (16 dims each)
    const int kbase = wv * 16 + kq * 4;
    float4 ev[4][4];
    #pragma unroll
    for (int m = 0; m < 4; ++m) {
        const float4* __restrict__ ep =
            (const float4*)(eh + (size_t)(kbase + m) * HD + ds * 16);
        #pragma unroll
        for (int j = 0; j < 4; ++j) ev[m][j] = ep[j];
    }
    const float cb0 = cbq[h * KK + kbase + 0];
    const float cb1 = cbq[h * KK + kbase + 1];
    const float cb2 = cbq[h * KK + kbase + 2];
    const float cb3 = cbq[h * KK + kbase + 3];

    // ---- Phase B: stage x-tile + isq (R6's exact pairwise order).
    // Wave wv handles tokens [wv*4, wv*4+4) only (exec-masked dedup).
    {
        const int tl = lane >> 1;
        const int hf = lane & 1;
        if ((tl >> 2) == wv) {         // implies tl < 16
            const float* __restrict__ xr =
                x + (size_t)(tok0 + tl) * DD + h * HD + hf * 128;
            float r0=0.f,r1=0.f,r2=0.f,r3=0.f,r4=0.f,r5=0.f,r6=0.f,r7=0.f;
            #pragma unroll
            for (int cc = 0; cc < 8; ++cc) {
                const float4 v0 = ((const float4*)xr)[cc * 4 + 0];
                const float4 v1 = ((const float4*)xr)[cc * 4 + 1];
                const float4 v2 = ((const float4*)xr)[cc * 4 + 2];
                const float4 v3 = ((const float4*)xr)[cc * 4 + 3];
                float* dst = x_lds + tl * XSTR + (hf * 8 + cc) * 20;
                ((float4*)dst)[0] = v0; ((float4*)dst)[1] = v1;
                ((float4*)dst)[2] = v2; ((float4*)dst)[3] = v3;
                {
                    #pragma clang fp contract(off)
                    r0 = r0 + v0.x*v0.x;  r1 = r1 + v0.y*v0.y;
                    r2 = r2 + v0.z*v0.z;  r3 = r3 + v0.w*v0.w;
                    r4 = r4 + v1.x*v1.x;  r5 = r5 + v1.y*v1.y;
                    r6 = r6 + v1.z*v1.z;  r7 = r7 + v1.w*v1.w;
                    r0 = r0 + v2.x*v2.x;  r1 = r1 + v2.y*v2.y;
                    r2 = r2 + v2.z*v2.z;  r3 = r3 + v2.w*v2.w;
                    r4 = r4 + v3.x*v3.x;  r5 = r5 + v3.y*v3.y;
                    r6 = r6 + v3.z*v3.z;  r7 = r7 + v3.w*v3.w;
                }
            }
            const float hs = ((r0 + r1) + (r2 + r3)) + ((r4 + r5) + (r6 + r7));
            const float ho = __shfl_xor(hs, 1);
            if (hf == 0) isq_lds[tl] = hs + ho;  // halfA + halfB, numpy order
        }
    }
    __syncthreads();

    // ---- Phase C: dot loop, 2 tokens per iteration (independent chains),
    // DPP all-reduce over the 16 ds-lanes (VALU pipe, zero LDS ops).
    #pragma unroll 1
    for (int t = 0; t < TPB; t += 2) {
        const float4* __restrict__ xbA =
            (const float4*)(x_lds + t * XSTR + ds * 20);
        const float4* __restrict__ xbB =
            (const float4*)(x_lds + (t + 1) * XSTR + ds * 20);
        float pA0=0.f, pA1=0.f, pA2=0.f, pA3=0.f;
        float pB0=0.f, pB1=0.f, pB2=0.f, pB3=0.f;
        #pragma unroll
        for (int j = 0; j < 4; ++j) {
            const float4 xA = xbA[j];
            const float4 xB = xbB[j];
            pA0 = __builtin_fmaf(ev[0][j].x, xA.x, pA0);
            pA0 = __builtin_fmaf(ev[0][j].y, xA.y, pA0);
            pA0 = __builtin_fmaf(ev[0][j].z, xA.z, pA0);
            pA0 = __builtin_fmaf(ev[0][j].w, xA.w, pA0);
            pA1 = __builtin_fmaf(ev[1][j].x, xA.x, pA1);
            pA1 = __builtin_fmaf(ev[1][j].y, xA.y, pA1);
            pA1 = __builtin_fmaf(ev[1][j].z, xA.z, pA1);
            pA1 = __builtin_fmaf(ev[1][j].w, xA.w, pA1);
            pA2 = __builtin_fmaf(ev[2][j].x, xA.x, pA2);
            pA2 = __builtin_fmaf(ev[2][j].y, xA.y, pA2);
            pA2 = __builtin_fmaf(ev[2][j].z, xA.z, pA2);
            pA2 = __builtin_fmaf(ev[2][j].w, xA.w, pA2);
            pA3 = __builtin_fmaf(ev[3][j].x, xA.x, pA3);
            pA3 = __builtin_fmaf(ev[3][j].y, xA.y, pA3);
            pA3 = __builtin_fmaf(ev[3][j].z, xA.z, pA3);
            pA3 = __builtin_fmaf(ev[3][j].w, xA.w, pA3);
            pB0 = __builtin_fmaf(ev[0][j].x, xB.x, pB0);
            pB0 = __builtin_fmaf(ev[0][j].y, xB.y, pB0);
            pB0 = __builtin_fmaf(ev[0][j].z, xB.z, pB0);
            pB0 = __builtin_fmaf(ev[0][j].w, xB.w, pB0);
            pB1 = __builtin_fmaf(ev[1][j].x, xB.x, pB1);
            pB1 = __builtin_fmaf(ev[1][j].y, xB.y, pB1);
            pB1 = __builtin_fmaf(ev[1][j].z, xB.z, pB1);
            pB1 = __builtin_fmaf(ev[1][j].w, xB.w, pB1);
            pB2 = __builtin_fmaf(ev[2][j].x, xB.x, pB2);
            pB2 = __builtin_fmaf(ev[2][j].y, xB.y, pB2);
            pB2 = __builtin_fmaf(ev[2][j].z, xB.z, pB2);
            pB2 = __builtin_fmaf(ev[2][j].w, xB.w, pB2);
            pB3 = __builtin_fmaf(ev[3][j].x, xB.x, pB3);
            pB3 = __builtin_fmaf(ev[3][j].y, xB.y, pB3);
            pB3 = __builtin_fmaf(ev[3][j].z, xB.z, pB3);
            pB3 = __builtin_fmaf(ev[3][j].w, xB.w, pB3);
        }
        pA0 = red16(pA0);  pA1 = red16(pA1);
        pA2 = red16(pA2);  pA3 = red16(pA3);
        pB0 = red16(pB0);  pB1 = red16(pB1);
        pB2 = red16(pB2);  pB3 = red16(pB3);
        if (ds == 0) {
            const float iqA = isq_lds[t];
            const float iqB = isq_lds[t + 1];
            float4 dA, dB;
            dA.x = (iqA + cb0) - 2.0f * pA0;
            dA.y = (iqA + cb1) - 2.0f * pA1;
            dA.z = (iqA + cb2) - 2.0f * pA2;
            dA.w = (iqA + cb3) - 2.0f * pA3;
            dB.x = (iqB + cb0) - 2.0f * pB0;
            dB.y = (iqB + cb1) - 2.0f * pB1;
            dB.z = (iqB + cb2) - 2.0f * pB2;
            dB.w = (iqB + cb3) - 2.0f * pB3;
            *(float4*)(dist_lds + t * DSTR + kbase) = dA;
            *(float4*)(dist_lds + (t + 1) * DSTR + kbase) = dB;
        }
    }
    __syncthreads();

    // ---- Phase D: per-token in-lane argmin (ascending k, strict < =>
    // exact numpy first-index). Lane t of wave 0 owns token t.
    if (wv == 0 && lane < TPB) {
        const int t = lane;
        const float* __restrict__ dr = dist_lds + t * DSTR;
        float f  = dr[0];
        int   fi = 0;
        #pragma unroll 8
        for (int kk = 1; kk < KK; ++kk) {
            const float v = dr[kk];
            const bool lt = v < f;
            f  = lt ? v  : f;
            fi = lt ? kk : fi;
        }
        out[NDQ + 1 + (size_t)(tok0 + t) * HH + h] = (float)fi;
        bi_lds[t] = fi;
        float ls = f;                    // min dist == ||q-x||^2 (~1e-6 rel)
        #pragma unroll
        for (int m = 1; m < TPB; m <<= 1) ls += __shfl_xor(ls, m);
        if (t == 0)
            partial[(size_t)h * NBX + blockIdx.x] = (double)ls;
    }
    __syncthreads();

    // ---- Phase E: q-row writes (4 rows/wave), gather from L2 codebook ----
    #pragma unroll
    for (int i = 0; i < TPB / 4; ++i) {
        const int row = wv * (TPB / 4) + i;
        const int kst = bi_lds[row];
        const float4 q4 = *(const float4*)(eh + (size_t)kst * HD + lane * 4);
        *(float4*)(out + (size_t)(tok0 + row) * DD + h * HD + lane * 4) = q4;
    }
}

__global__ void vq_finalize(const double* __restrict__ partial,
                            float* __restrict__ out)
{
    const int lane = threadIdx.x & 63;
    double s = 0.0;
    for (int i = 0; i < NPART / 64; ++i) s += partial[i * 64 + lane];
    #pragma unroll
    for (int m = 1; m < 64; m <<= 1) s += __shfl_xor(s, m);
    if (lane == 0) {
        const float mv = (float)(s / (double)NDQ);
        out[NDQ] = mv + 0.5f * mv;   // q_latent + 0.5*e_latent (equal values)
    }
}

extern "C" void kernel_launch(void* const* d_in, const int* in_sizes, int n_in,
                              void* d_out, int out_size, void* d_ws, size_t ws_size,
                              hipStream_t stream)
{
    const float* x   = (const float*)d_in[0];
    const float* emb = (const float*)d_in[1];
    float* out = (float*)d_out;
    double* partial = (double*)d_ws;                       // 8192 doubles
    float*  cbq     = (float*)((char*)d_ws + NPART * 8);   // 256 floats

    vq_cbq<<<1, dim3(256), 0, stream>>>(emb, cbq);
    vq_main<<<dim3(NBX, HH), dim3(256), 0, stream>>>(x, emb, cbq, out, partial);
    vq_finalize<<<1, dim3(64), 0, stream>>>(partial, out);
}